// Round 1
// baseline (793.478 us; speedup 1.0000x reference)
//
#include <hip/hip_runtime.h>
#include <math.h>

// EqualityConstraint: x_new = x - J^T G^{-1} F(x)
//   t = tanh(x); s = 1 - t^2; J = A diag(s)
//   F = A t + p; G = A diag(s^2) A^T  (SPD, M x M)
//   y = G^{-1} F;  x_new = x - s .* (A^T y)
// (Derived from the reference: QR/projection algebra collapses to a
//  Gauss-Newton step; see session notes.)
//
// One 256-thread block per batch row. Threads form a 16x16 grid; each owns
// an 8x8 register tile of G. Blocked register Cholesky (8-wide panels),
// L stored column-major in LDS (Lc[k][i] = L[i][k], pitch 132).

#define kN 256   // x dim
#define kM 128   // constraint dim
#define LCP 132  // Lc row pitch (floats): 132*4B = 528B, 16B-aligned rows
#define STP 132  // stage row pitch

__global__ __launch_bounds__(256, 2)
void eqcon_kernel(const float* __restrict__ x,
                  const float* __restrict__ parms,
                  const float* __restrict__ A,
                  float* __restrict__ out)
{
    __shared__ float t_s[kN];
    __shared__ float s_s[kN];
    __shared__ float Fx_s[kM];
    __shared__ float z_s[kM];
    __shared__ float y_s[kM];
    __shared__ float invd_s[kM];
    __shared__ float Ld_s[64];
    __shared__ float Lc[kM][LCP];     // Lc[k][i] = L[i][k]
    __shared__ float stage[16 * STP]; // stage[jj][i] = A[i][jt+jj]

    const int tid = (int)threadIdx.x;
    const int b   = (int)blockIdx.x;
    const int ti  = tid & 15;   // row-tile index
    const int tk  = tid >> 4;   // col-tile index

    // ---- Phase 1: t = tanh(x), s = sech^2(x) ----
    const float xv = x[b * kN + tid];
    const float tv = tanhf(xv);
    const float sv = 1.0f - tv * tv;
    t_s[tid] = tv;
    s_s[tid] = sv;
    __syncthreads();

    // ---- Phase 2: Fx = A t + parms (2 threads per row) ----
    {
        const int row  = tid >> 1;
        const int half = tid & 1;
        const float4* __restrict__ Ar =
            reinterpret_cast<const float4*>(A + row * kN + half * (kN / 2));
        const float4* Tr = reinterpret_cast<const float4*>(t_s + half * (kN / 2));
        float sum = 0.0f;
#pragma unroll
        for (int q = 0; q < kN / 8; ++q) {
            const float4 a4 = Ar[q];
            const float4 t4 = Tr[q];
            sum += a4.x * t4.x + a4.y * t4.y + a4.z * t4.z + a4.w * t4.w;
        }
        sum += __shfl_xor(sum, 1);
        if (half == 0) Fx_s[row] = sum + parms[b * kM + row];
    }

    // ---- Phase 3: G = A diag(s^2) A^T, each thread an 8x8 register tile ----
    float acc[8][8];
#pragma unroll
    for (int r = 0; r < 8; ++r)
#pragma unroll
        for (int c = 0; c < 8; ++c) acc[r][c] = 0.0f;

    for (int jt = 0; jt < kN; jt += 16) {
        __syncthreads();  // prev tile's compute done before overwriting stage
#pragma unroll
        for (int rep = 0; rep < 8; ++rep) {
            const int idx = rep * 256 + tid;
            const int i   = idx >> 4;
            const int jj  = idx & 15;
            stage[jj * STP + i] = A[i * kN + (jt + jj)];
        }
        __syncthreads();
#pragma unroll
        for (int jj = 0; jj < 16; ++jj) {
            const float sj = s_s[jt + jj];
            const float w  = sj * sj;
            const float* rowp = stage + jj * STP;
            const float4 a0 = *reinterpret_cast<const float4*>(rowp + ti * 8);
            const float4 a1 = *reinterpret_cast<const float4*>(rowp + ti * 8 + 4);
            const float4 b0 = *reinterpret_cast<const float4*>(rowp + tk * 8);
            const float4 b1 = *reinterpret_cast<const float4*>(rowp + tk * 8 + 4);
            const float av[8] = {a0.x, a0.y, a0.z, a0.w, a1.x, a1.y, a1.z, a1.w};
            const float bv[8] = {b0.x * w, b0.y * w, b0.z * w, b0.w * w,
                                 b1.x * w, b1.y * w, b1.z * w, b1.w * w};
#pragma unroll
            for (int r = 0; r < 8; ++r)
#pragma unroll
                for (int c = 0; c < 8; ++c) acc[r][c] += av[r] * bv[c];
        }
    }
    __syncthreads();

    // ---- Phase 4: blocked register Cholesky, panels of 8 columns ----
    for (int pb = 0; pb < 16; ++pb) {
        const int kb = pb * 8;
        if (ti == pb && tk == pb) {
            // 8x8 diagonal Cholesky in registers (lower triangle)
#pragma unroll
            for (int kk = 0; kk < 8; ++kk) {
                float d = fmaxf(acc[kk][kk], 1e-30f);
                const float rd  = sqrtf(d);
                const float inv = 1.0f / rd;
                invd_s[kb + kk] = inv;
                acc[kk][kk] = rd;
#pragma unroll
                for (int r = kk + 1; r < 8; ++r) acc[r][kk] *= inv;
#pragma unroll
                for (int r = kk + 1; r < 8; ++r)
#pragma unroll
                    for (int c = kk + 1; c <= r; ++c)
                        acc[r][c] -= acc[r][kk] * acc[c][kk];
            }
#pragma unroll
            for (int r = 0; r < 8; ++r)
#pragma unroll
                for (int c = 0; c < 8; ++c) {
                    Ld_s[r * 8 + c]      = acc[r][c];
                    Lc[kb + c][kb + r]   = acc[r][c];  // upper part garbage, never read
                }
        }
        __syncthreads();
        if (tk == pb && ti > pb) {
            // panel solve: B := B * Ld^{-T}
#pragma unroll
            for (int c = 0; c < 8; ++c) {
#pragma unroll
                for (int m = 0; m < 8; ++m) {
                    if (m < c) {
                        const float coef = Ld_s[c * 8 + m];
#pragma unroll
                        for (int r = 0; r < 8; ++r) acc[r][c] -= acc[r][m] * coef;
                    }
                }
                const float inv = invd_s[kb + c];
#pragma unroll
                for (int r = 0; r < 8; ++r) acc[r][c] *= inv;
            }
#pragma unroll
            for (int c = 0; c < 8; ++c)
#pragma unroll
                for (int r = 0; r < 8; ++r) Lc[kb + c][ti * 8 + r] = acc[r][c];
        }
        __syncthreads();
        if (ti > pb && tk > pb) {
            // rank-8 trailing update from the freshly written panel
#pragma unroll
            for (int m = 0; m < 8; ++m) {
                const float* lr = &Lc[kb + m][0];
                const float4 c0 = *reinterpret_cast<const float4*>(lr + ti * 8);
                const float4 c1 = *reinterpret_cast<const float4*>(lr + ti * 8 + 4);
                const float4 d0 = *reinterpret_cast<const float4*>(lr + tk * 8);
                const float4 d1 = *reinterpret_cast<const float4*>(lr + tk * 8 + 4);
                const float cl[8] = {c0.x, c0.y, c0.z, c0.w, c1.x, c1.y, c1.z, c1.w};
                const float cc[8] = {d0.x, d0.y, d0.z, d0.w, d1.x, d1.y, d1.z, d1.w};
#pragma unroll
                for (int r = 0; r < 8; ++r)
#pragma unroll
                    for (int c = 0; c < 8; ++c) acc[r][c] -= cl[r] * cc[c];
            }
        }
        // no barrier needed here: next panel's writes touch disjoint LDS rows
    }
    __syncthreads();

    // ---- Phase 5: triangular solves on wave 0 (2 rows per lane) ----
    if (tid < 64) {
        const int r0 = tid;
        const int r1 = tid + 64;
        float a0 = Fx_s[r0];
        float a1 = Fx_s[r1];
        // forward: L z = Fx   (L[i][k] = Lc[k][i], row-contiguous reads)
        for (int k = 0; k < kM; ++k) {
            const float srcv = (k < 64) ? a0 : a1;
            const float zk = __shfl(srcv, k & 63) * invd_s[k];
            if (tid == (k & 63)) z_s[k] = zk;
            const float l0 = Lc[k][r0];
            const float l1 = Lc[k][r1];
            if (r0 > k) a0 -= l0 * zk;
            if (r1 > k) a1 -= l1 * zk;
        }
        a0 = z_s[r0];
        a1 = z_s[r1];
        // backward: L^T y = z  (L[k][i] = Lc[i][k], stride-LCP column reads)
        for (int k = kM - 1; k >= 0; --k) {
            const float srcv = (k < 64) ? a0 : a1;
            const float yk = __shfl(srcv, k & 63) * invd_s[k];
            if (tid == (k & 63)) y_s[k] = yk;
            const float u0 = Lc[r0][k];
            const float u1 = Lc[r1][k];
            if (r0 < k) a0 -= u0 * yk;
            if (r1 < k) a1 -= u1 * yk;
        }
    }
    __syncthreads();

    // ---- Phase 6: x_new = x - s .* (A^T y) (coalesced over columns) ----
    {
        float sum = 0.0f;
#pragma unroll 8
        for (int i = 0; i < kM; ++i) sum += A[i * kN + tid] * y_s[i];
        out[b * kN + tid] = xv - sv * sum;
    }
}

extern "C" void kernel_launch(void* const* d_in, const int* in_sizes, int n_in,
                              void* d_out, int out_size, void* d_ws, size_t ws_size,
                              hipStream_t stream) {
    const float* x     = (const float*)d_in[0];
    const float* parms = (const float*)d_in[1];
    const float* A     = (const float*)d_in[2];
    float* out = (float*)d_out;
    const int Bcount = in_sizes[0] / kN;  // 2048
    eqcon_kernel<<<dim3(Bcount), dim3(256), 0, stream>>>(x, parms, A, out);
}